// Round 3
// baseline (592.555 us; speedup 1.0000x reference)
//
#include <hip/hip_runtime.h>
#include <cstdint>
#include <cstddef>

#define N_NODES 8192
#define N_EDGES 262144
#define INPUT_DIM 512
#define HIDDEN 128
#define ALPHA 0.5f
#define EOS 1e-10f
#define BCAP 128

typedef float v4 __attribute__((ext_vector_type(4)));
typedef __attribute__((ext_vector_type(8))) short short8;
typedef __attribute__((ext_vector_type(4))) float floatx4;

__device__ inline unsigned short f2bf(float x) {
    unsigned u = __builtin_bit_cast(unsigned, x);
    return (unsigned short)((u + 0x7FFFu + ((u >> 16) & 1u)) >> 16);
}

// Load 8 consecutive f32 and convert to a bf16x8 MFMA fragment in-register
// (same f2bf rounding as the old k0 pass -> bit-identical results).
__device__ inline short8 ld8bf(const float* __restrict__ p) {
    float4 u = *(const float4*)p;
    float4 v = *(const float4*)(p + 4);
    short8 r;
    r[0] = (short)f2bf(u.x); r[1] = (short)f2bf(u.y);
    r[2] = (short)f2bf(u.z); r[3] = (short)f2bf(u.w);
    r[4] = (short)f2bf(v.x); r[5] = (short)f2bf(v.y);
    r[6] = (short)f2bf(v.z); r[7] = (short)f2bf(v.w);
    return r;
}

// K1 (now also does k0's job): g[n] = sum_h relu(F[n]·W[h]+bemb[h]) *
// (Wedge[h]+Wedge[128+h]). 512 blocks x 256 threads (4 waves). Block = 16
// nodes; wave = 32 hidden (2 MFMA tiles) x full K. Fragments loaded DIRECTLY
// from global f32 and packed to bf16 in-register — no staging pass, no LDS,
// no barriers in the K-loop. Also zeroes cnt (done before k_edge launches).
__global__ __launch_bounds__(256) void k1_g(
    const float* __restrict__ F, const float* __restrict__ W,
    const float* __restrict__ bemb, const float* __restrict__ Wedge,
    float* __restrict__ g, int* __restrict__ cnt)
{
    __shared__ float part[4][16];
    int tid = threadIdx.x;
    int node0 = blockIdx.x * 16;
    if (tid < 16) cnt[node0 + tid] = 0;
    int lane = tid & 63, wave = tid >> 6;
    int ml = lane & 15, q = lane >> 4;
    int h0 = wave * 32;

    const float* Ap  = &F[(size_t)(node0 + ml) * INPUT_DIM + q * 8];
    const float* Bp0 = &W[(size_t)(h0 + ml) * INPUT_DIM + q * 8];
    const float* Bp1 = &W[(size_t)(h0 + 16 + ml) * INPUT_DIM + q * 8];

    floatx4 acc0 = 0.f, acc1 = 0.f;
#pragma unroll 4
    for (int s = 0; s < 16; s++) {
        short8 a  = ld8bf(Ap  + s * 32);
        short8 b0 = ld8bf(Bp0 + s * 32);
        short8 b1 = ld8bf(Bp1 + s * 32);
        acc0 = __builtin_amdgcn_mfma_f32_16x16x32_bf16(a, b0, acc0, 0, 0, 0);
        acc1 = __builtin_amdgcn_mfma_f32_16x16x32_bf16(a, b1, acc1, 0, 0, 0);
    }
    // C/D: col(=hidden-in-tile)=ml, row(=node-in-tile)=q*4+reg
    float sr[4] = {0.f, 0.f, 0.f, 0.f};
#pragma unroll
    for (int t = 0; t < 2; t++) {
        int h = h0 + t * 16 + ml;
        float uu = Wedge[h] + Wedge[HIDDEN + h];
        float bb = bemb[h];
        floatx4 ac = t ? acc1 : acc0;
#pragma unroll
        for (int rg = 0; rg < 4; rg++) {
            float hv = ac[rg] + bb;
            sr[rg] += (hv > 0.f ? hv : 0.f) * uu;
        }
    }
#pragma unroll
    for (int m = 1; m < 16; m <<= 1) {
#pragma unroll
        for (int rg = 0; rg < 4; rg++) sr[rg] += __shfl_xor(sr[rg], m, 64);
    }
    if (ml == 0) {
#pragma unroll
        for (int rg = 0; rg < 4; rg++) part[wave][q * 4 + rg] = sr[rg];
    }
    __syncthreads();
    if (tid < 16)
        g[node0 + tid] = part[0][tid] + part[1][tid] + part[2][tid] + part[3][tid];
}

// K2: per-edge weight + packed bucket scatter: (col<<18)|idx and w as one int2.
__global__ __launch_bounds__(256) void k_edge(
    const int* __restrict__ edges, const float* __restrict__ noise,
    const float* __restrict__ g, const float* __restrict__ bedge,
    float* __restrict__ wlp, float* __restrict__ whp,
    int* __restrict__ cnt, int2* __restrict__ buck)
{
    int i = blockIdx.x * 256 + threadIdx.x;
    int e0 = edges[i], e1 = edges[N_EDGES + i];
    float raw = 0.5f * (g[e0] + g[e1]) + bedge[0];
    float eps = -0.9998f * noise[i] + 0.9999f;
    float gate = logf(eps) - log1pf(-eps) + raw;
    float w = 1.f / (1.f + expf(-gate));
    wlp[i] = w;
    whp[i] = 1.f - w;
    int pos = atomicAdd(&cnt[e0], 1);
    if (pos < BCAP) {
        int2 pw;
        pw.x = (e1 << 18) | i;
        pw.y = __builtin_bit_cast(int, w);
        buck[e0 * BCAP + pos] = pw;
    }
}

// K3: winner resolution + degrees -> inv factors. 2 rows/block.
// Winner = max packed value among same col (col in high bits, idx in low).
// Rewrites buck.x: winner -> col (>=0), loser -> -1 (w stays in buck.y).
__global__ __launch_bounds__(256) void k_deginv(
    const int* __restrict__ cnt, int2* __restrict__ buck,
    float* __restrict__ inv_lp, float* __restrict__ inv_hp)
{
    __shared__ int s_pv[2][BCAP];
    __shared__ float plp[4], php[4];
    int tid = threadIdx.x;
    int half = tid >> 7, lt = tid & 127;
    int r = blockIdx.x * 2 + half;
    int d = cnt[r]; if (d > BCAP) d = BCAP;
    int2 pw; pw.x = -1; pw.y = 0;
    if (lt < d) {
        pw = buck[r * BCAP + lt];
        s_pv[half][lt] = pw.x;
    }
    __syncthreads();
    float sl = 0.f, sh = 0.f;
    if (lt < d) {
        int pv = pw.x, c = pv >> 18;
        bool win = true;
        for (int j = 0; j < d; j++) {
            int o = s_pv[half][j];
            if ((o >> 18) == c && o > pv) { win = false; break; }
        }
        if (win) {
            float w = __builtin_bit_cast(float, pw.y);
            sl = w; sh = 1.f - w;
            pw.x = c;
        } else {
            pw.x = -1;
        }
        buck[r * BCAP + lt] = pw;
    }
#pragma unroll
    for (int m = 1; m < 64; m <<= 1) {
        sl += __shfl_xor(sl, m, 64);
        sh += __shfl_xor(sh, m, 64);
    }
    int wv = tid >> 6;
    if ((tid & 63) == 0) { plp[wv] = sl; php[wv] = sh; }
    __syncthreads();
    if (lt == 0) {
        float l = plp[half * 2] + plp[half * 2 + 1];
        float h = php[half * 2] + php[half * 2 + 1];
        inv_lp[r] = 1.f / (sqrtf(l + 1.f) + EOS);
        inv_hp[r] = 1.f / (sqrtf(h + 1.f) + EOS);
    }
}

// K4: one block per row, emits BOTH LP and HP rows. O(1) col->entry LDS LUT.
// Stores are PLAIN (not NT) this round: the rocclr fill proves plain streaming
// stores hit 6.2 TB/s; round-1 evidence suggests NT underperforms.
__global__ __launch_bounds__(256) void k_fill(
    const int* __restrict__ cnt, const int2* __restrict__ buck,
    const float* __restrict__ inv_lp, const float* __restrict__ inv_hp,
    float* __restrict__ LP, float* __restrict__ HP)
{
    __shared__ unsigned bm[256];              // 8192 col bits
    __shared__ unsigned char s_ent[N_NODES];  // col -> entry index (valid iff bit set)
    __shared__ float s_vlp[BCAP + 1];
    __shared__ float s_vhp[BCAP + 1];
    int r = blockIdx.x, tid = threadIdx.x;
    bm[tid] = 0;
    int d = cnt[r]; if (d > BCAP) d = BCAP;
    float irl = inv_lp[r], irh = inv_hp[r];
    __syncthreads();
    if (tid < d) {
        int2 pw = buck[r * BCAP + tid];
        int c = pw.x;
        if (c >= 0) {
            float w = __builtin_bit_cast(float, pw.y);
            float icl = inv_lp[c], ich = inv_hp[c];
            float diag = (c == r) ? 1.f : 0.f;
            s_vlp[tid] = (w + diag) * irl * icl;
            s_vhp[tid] = diag - ((1.f - w) + diag) * irh * ich * ALPHA;
            s_ent[c] = (unsigned char)tid;    // unique: one winner per col
            atomicOr(&bm[c >> 5], 1u << (c & 31));
        }
    }
    __syncthreads();
    if (tid == 0) {
        if (!((bm[r >> 5] >> (r & 31)) & 1u)) {   // no self-edge: background diagonal
            s_vlp[d] = irl * irl; s_vhp[d] = 1.0f;
            s_ent[r] = (unsigned char)d;
            bm[r >> 5] |= 1u << (r & 31);
        }
    }
    __syncthreads();
    float* LPr = LP + (size_t)r * N_NODES;
    float* HPr = HP + (size_t)r * N_NODES;
#pragma unroll
    for (int i = 0; i < 8; i++) {
        int ch = i * 256 + tid;               // chunk of 4 cols
        unsigned nib = (bm[ch >> 3] >> ((ch & 7) * 4)) & 0xFu;
        v4 lp = 0.f, hp = 0.f;
        if (nib) {
#pragma unroll
            for (int sl = 0; sl < 4; sl++) {
                if (nib & (1u << sl)) {
                    int e = s_ent[ch * 4 + sl];
                    ((float*)&lp)[sl] = s_vlp[e];
                    ((float*)&hp)[sl] = s_vhp[e];
                }
            }
        }
        *(v4*)&LPr[ch * 4] = lp;
        *(v4*)&HPr[ch * 4] = hp;
    }
}

extern "C" void kernel_launch(void* const* d_in, const int* in_sizes, int n_in,
                              void* d_out, int out_size, void* d_ws, size_t ws_size,
                              hipStream_t stream) {
    const float* F     = (const float*)d_in[0];
    const float* W     = (const float*)d_in[1];
    const float* bemb  = (const float*)d_in[2];
    const float* Wedge = (const float*)d_in[3];
    const float* bedge = (const float*)d_in[4];
    const float* noise = (const float*)d_in[5];
    const int*   edges = (const int*)d_in[6];

    const size_t N2 = (size_t)N_NODES * N_NODES;
    float* out = (float*)d_out;
    float* LP  = out;
    float* HP  = out + N2;
    float* wlp = HP + N2;
    float* whp = wlp + N_EDGES;

    // ws: g(32K) | cnt(32K) | inv_lp(32K) | inv_hp(32K) | buck(8M)
    char* ws = (char*)d_ws;
    float* g      = (float*)(ws);
    int*   cnt    = (int*)  (ws + 32768);
    float* inv_lp = (float*)(ws + 65536);
    float* inv_hp = (float*)(ws + 98304);
    int2*  buck   = (int2*) (ws + 131072);

    k1_g<<<512, 256, 0, stream>>>(F, W, bemb, Wedge, g, cnt);
    k_edge<<<N_EDGES / 256, 256, 0, stream>>>(edges, noise, g, bedge,
                                              wlp, whp, cnt, buck);
    k_deginv<<<N_NODES / 2, 256, 0, stream>>>(cnt, buck, inv_lp, inv_hp);
    k_fill<<<N_NODES, 256, 0, stream>>>(cnt, buck, inv_lp, inv_hp, LP, HP);
}